// Round 8
// baseline (62.452 us; speedup 1.0000x reference)
//
#include <hip/hip_runtime.h>
#include <hip/hip_bf16.h>

typedef __attribute__((ext_vector_type(8))) short bf16x8;
typedef __attribute__((ext_vector_type(4))) float f32x4;
typedef unsigned short u16;
typedef unsigned int u32;

#define NH 8
#define NN 4096
#define MM 4096

__device__ __forceinline__ u16 f2bf(float f) {
  u32 b = __float_as_uint(f);
  b += 0x7FFFu + ((b >> 16) & 1u);   // RNE to bf16
  return (u16)(b >> 16);
}

// pack two positive floats to bf16 pair {lo:a, hi:b}, round-half-up
__device__ __forceinline__ u32 pack_rnu(float a, float b) {
  u32 ua = __float_as_uint(a) + 0x8000u;
  u32 ub = __float_as_uint(b) + 0x8000u;
#if __has_builtin(__builtin_amdgcn_perm)
  return __builtin_amdgcn_perm(ub, ua, 0x07060302u);  // {ua.b2,ua.b3,ub.b2,ub.b3}
#else
  return (ua >> 16) | (ub & 0xFFFF0000u);
#endif
}

#if __has_builtin(__builtin_amdgcn_exp2f)
__device__ __forceinline__ float exp2_fast(float x) { return __builtin_amdgcn_exp2f(x); }
#else
__device__ __forceinline__ float exp2_fast(float x) { return __expf(x * 0.69314718055994531f); }
#endif

// ---------------- fused projections: blocks 0..255 = q/k, 256..383 = v ----------------
// v is written transposed AND key-permuted within each 32-key chunk:
//   position p (0..31) holds key k(p) = 16*((p>>2)&1) + 4*(p>>3) + (p&3)
// so flash's PV A-fragment (slot map k = 4g+(j&3)+16(j>>2)) is one b128 at 8g.
__global__ __launch_bounds__(256) void proj_kernel(
    const float* __restrict__ x, const float* __restrict__ y,
    const float* __restrict__ Wq, const float* __restrict__ bq,
    const float* __restrict__ Wk, const float* __restrict__ bk,
    const float* __restrict__ Wv, const float* __restrict__ bv,
    u16* __restrict__ qs, u16* __restrict__ ks, u16* __restrict__ vT)
{
  __shared__ u16 sv[256][33];
  const int bid = blockIdx.x;
  const int tid = threadIdx.x;
  if (bid < 256) {
    // ---- q/k path ----
    int idx = bid * 256 + tid;                  // 65536 total
    int t = idx >> 15;                          // 0 = q (from x), 1 = k (from y)
    int h = (idx >> 12) & 7;
    int row = idx & 4095;
    const float* src = (t ? y : x) + row * 16;
    const float* W = (t ? Wk : Wq) + (h << 9);
    const float* b = (t ? bk : bq) + (h << 5);
    // q scale = (1/sqrt(32)) * log2(e) so softmax is exp2(score)
    const float scale = t ? 1.0f : 0.25503635116465163f;
    float4 r4[4];
#pragma unroll
    for (int i = 0; i < 4; ++i) r4[i] = ((const float4*)src)[i];
    const float* r = (const float*)r4;
    u16* out = (t ? ks : qs) + (idx & 32767) * 32;      // (h*4096+row)*32
#pragma unroll
    for (int j = 0; j < 32; ++j) {
      float a = b[j];
#pragma unroll
      for (int i = 0; i < 16; ++i) a = fmaf(r[i], W[i * 32 + j], a);
      out[j] = f2bf(a * scale);
    }
  } else {
    // ---- v path ----
    int vb = bid - 256;
    int h = vb >> 4;
    int kb = (vb & 15) << 8;           // 256 keys per block
    const float* src = y + (kb + tid) * 16;
    const float* W = Wv + (h << 9);
    const float* b = bv + (h << 5);
    float4 r4[4];
#pragma unroll
    for (int i = 0; i < 4; ++i) r4[i] = ((const float4*)src)[i];
    const float* r = (const float*)r4;
#pragma unroll
    for (int j = 0; j < 32; ++j) {
      float a = b[j];
#pragma unroll
      for (int i = 0; i < 16; ++i) a = fmaf(r[i], W[i * 32 + j], a);
      sv[tid][j] = f2bf(a);
    }
    __syncthreads();
    int dv = tid >> 3;
    int c = (tid & 7) << 5;            // 32-key chunk
    u16* dst = vT + (((h << 5) + dv) << 12) + kb + c;
#pragma unroll
    for (int q = 0; q < 4; ++q) {      // positions 8q..8q+7 <- keys {4q+r, 16+4q+r}
      uint4 w;
      w.x = (u32)sv[c + 4 * q + 0][dv]      | ((u32)sv[c + 4 * q + 1][dv] << 16);
      w.y = (u32)sv[c + 4 * q + 2][dv]      | ((u32)sv[c + 4 * q + 3][dv] << 16);
      w.z = (u32)sv[c + 16 + 4 * q + 0][dv] | ((u32)sv[c + 16 + 4 * q + 1][dv] << 16);
      w.w = (u32)sv[c + 16 + 4 * q + 2][dv] | ((u32)sv[c + 16 + 4 * q + 3][dv] << 16);
      *(uint4*)(dst + q * 8) = w;
    }
  }
}

// ---------------- flash attention (key-split partials): S^T = K Q^T, O^T = V^T P^T ----
// Round-7 verified structure (2 q-tiles/wave, KVBLK=128, reg prefetch).
// NEW: denominator via ones-row MFMA (row 0 of A = 1 -> accL.x lanes g==0
// hold col sums of P); removes per-tile VALU adds and end shfls.
#define KST 40                  // K LDS row stride in u16 (80 B, 16B-aligned)
#define VST 72                  // V LDS row stride in u16 (144 B, 16B-aligned)
#define VSZ (32 * VST)          // one 64-key V sub-tile

__global__ __launch_bounds__(256) void flash_kernel(
    const u16* __restrict__ qs, const u16* __restrict__ ksrc,
    const u16* __restrict__ vT, float* __restrict__ accP,
    float* __restrict__ lsumP)
{
  __shared__ u16 sK[128 * KST];    // 128 keys x 32 dq  (10240 B)
  __shared__ u16 sVT[2 * VSZ];     // 2 sub x 32 dv x 64 keys (9216 B)
  const int h = blockIdx.y;
  const int qt = blockIdx.x;
  const int z = blockIdx.z;
  const int nIter = (MM / 128) / gridDim.z;        // stages of 128 keys
  const int kb0 = z * (MM / gridDim.z);            // first key of this split
  const int tid = threadIdx.x;
  const int wv = tid >> 6;
  const int lane = tid & 63;
  const int d = lane & 15;        // qrow-in-16 / A-row index / C col
  const int g = lane >> 4;        // lane group
  const int qrowA = (qt << 7) + (wv << 5) + d;     // wave owns rows [wv*32, wv*32+32)
  const int qrowB = qrowA + 16;

  union U4 { uint4 q; bf16x8 v; };
  // Q fragments, contiguous k-relabel: slot (g,j) -> k = 8g+j (same map on K side)
  U4 qfA, qfB;
  qfA.q = *(const uint4*)(qs + (((h << 12) + qrowA) << 5) + (g << 3));
  qfB.q = *(const uint4*)(qs + (((h << 12) + qrowB) << 5) + (g << 3));

  // ones-row matrix for lsum MFMA: A[0][k]=1 (bijection-independent), rows>0 = 0
  union { u32 w[4]; bf16x8 v; } ones;
  {
    u32 ow = (d == 0) ? 0x3F803F80u : 0u;
    ones.w[0] = ow; ones.w[1] = ow; ones.w[2] = ow; ones.w[3] = ow;
  }

  f32x4 accA0 = {0.f, 0.f, 0.f, 0.f}, accA1 = {0.f, 0.f, 0.f, 0.f};
  f32x4 accB0 = {0.f, 0.f, 0.f, 0.f}, accB1 = {0.f, 0.f, 0.f, 0.f};
  f32x4 accLA = {0.f, 0.f, 0.f, 0.f}, accLB = {0.f, 0.f, 0.f, 0.f};
  const f32x4 zero = {0.f, 0.f, 0.f, 0.f};

  // staging addresses
  const u16* gK = ksrc + (h << 17) + (kb0 << 5) + ((tid >> 1) << 5) + ((tid & 1) << 4);
  const u16* gV = vT + (((h << 5) + (tid >> 3)) << 12) + kb0 + ((tid & 7) << 4);
  u16* wK = sK + (tid >> 1) * KST + ((tid & 1) << 4);
  u16* wV = sVT + ((tid & 7) >> 2) * VSZ + (tid >> 3) * VST + ((tid & 7) & 3) * 16;

  // prologue: stage this split's first 128 keys
  {
    uint4 a = *(const uint4*)gK, b = *(const uint4*)(gK + 8);
    uint4 c = *(const uint4*)gV, e = *(const uint4*)(gV + 8);
    *(uint4*)wK = a; *(uint4*)(wK + 8) = b;
    *(uint4*)wV = c; *(uint4*)(wV + 8) = e;
  }
  __syncthreads();

  auto compute = [&](const u16* kb, const u16* vb) {
    U4 kf[4];
#pragma unroll
    for (int t = 0; t < 4; ++t)     // K frags: keys 16t+d, k = 8g+j contiguous
      kf[t].q = *(const uint4*)(kb + (t * 16 + d) * KST + (g << 3));

    union { u32 w[4]; bf16x8 v; } pbA0, pbA1, pbB0, pbB1;
    {
      f32x4 s0, s1, s2, s3;
      s0 = __builtin_amdgcn_mfma_f32_16x16x32_bf16(kf[0].v, qfA.v, zero, 0, 0, 0);
      s1 = __builtin_amdgcn_mfma_f32_16x16x32_bf16(kf[1].v, qfA.v, zero, 0, 0, 0);
      s2 = __builtin_amdgcn_mfma_f32_16x16x32_bf16(kf[2].v, qfA.v, zero, 0, 0, 0);
      s3 = __builtin_amdgcn_mfma_f32_16x16x32_bf16(kf[3].v, qfA.v, zero, 0, 0, 0);
      float e[16];
      e[0]=exp2_fast(s0.x); e[1]=exp2_fast(s0.y); e[2]=exp2_fast(s0.z); e[3]=exp2_fast(s0.w);
      e[4]=exp2_fast(s1.x); e[5]=exp2_fast(s1.y); e[6]=exp2_fast(s1.z); e[7]=exp2_fast(s1.w);
      e[8]=exp2_fast(s2.x); e[9]=exp2_fast(s2.y); e[10]=exp2_fast(s2.z); e[11]=exp2_fast(s2.w);
      e[12]=exp2_fast(s3.x); e[13]=exp2_fast(s3.y); e[14]=exp2_fast(s3.z); e[15]=exp2_fast(s3.w);
      pbA0.w[0] = pack_rnu(e[0], e[1]);   pbA0.w[1] = pack_rnu(e[2], e[3]);
      pbA0.w[2] = pack_rnu(e[4], e[5]);   pbA0.w[3] = pack_rnu(e[6], e[7]);
      pbA1.w[0] = pack_rnu(e[8], e[9]);   pbA1.w[1] = pack_rnu(e[10], e[11]);
      pbA1.w[2] = pack_rnu(e[12], e[13]); pbA1.w[3] = pack_rnu(e[14], e[15]);
    }
    {
      f32x4 s0, s1, s2, s3;
      s0 = __builtin_amdgcn_mfma_f32_16x16x32_bf16(kf[0].v, qfB.v, zero, 0, 0, 0);
      s1 = __builtin_amdgcn_mfma_f32_16x16x32_bf16(kf[1].v, qfB.v, zero, 0, 0, 0);
      s2 = __builtin_amdgcn_mfma_f32_16x16x32_bf16(kf[2].v, qfB.v, zero, 0, 0, 0);
      s3 = __builtin_amdgcn_mfma_f32_16x16x32_bf16(kf[3].v, qfB.v, zero, 0, 0, 0);
      float e[16];
      e[0]=exp2_fast(s0.x); e[1]=exp2_fast(s0.y); e[2]=exp2_fast(s0.z); e[3]=exp2_fast(s0.w);
      e[4]=exp2_fast(s1.x); e[5]=exp2_fast(s1.y); e[6]=exp2_fast(s1.z); e[7]=exp2_fast(s1.w);
      e[8]=exp2_fast(s2.x); e[9]=exp2_fast(s2.y); e[10]=exp2_fast(s2.z); e[11]=exp2_fast(s2.w);
      e[12]=exp2_fast(s3.x); e[13]=exp2_fast(s3.y); e[14]=exp2_fast(s3.z); e[15]=exp2_fast(s3.w);
      pbB0.w[0] = pack_rnu(e[0], e[1]);   pbB0.w[1] = pack_rnu(e[2], e[3]);
      pbB0.w[2] = pack_rnu(e[4], e[5]);   pbB0.w[3] = pack_rnu(e[6], e[7]);
      pbB1.w[0] = pack_rnu(e[8], e[9]);   pbB1.w[1] = pack_rnu(e[10], e[11]);
      pbB1.w[2] = pack_rnu(e[12], e[13]); pbB1.w[3] = pack_rnu(e[14], e[15]);
    }
    // denominators on the MFMA pipe (row 0 = sum over keys)
    accLA = __builtin_amdgcn_mfma_f32_16x16x32_bf16(ones.v, pbA0.v, accLA, 0, 0, 0);
    accLA = __builtin_amdgcn_mfma_f32_16x16x32_bf16(ones.v, pbA1.v, accLA, 0, 0, 0);
    accLB = __builtin_amdgcn_mfma_f32_16x16x32_bf16(ones.v, pbB0.v, accLB, 0, 0, 0);
    accLB = __builtin_amdgcn_mfma_f32_16x16x32_bf16(ones.v, pbB1.v, accLB, 0, 0, 0);
    // V frags (vT key-permuted: group-g slot block at position 8g), serve both halves
    U4 vf0, vf1, vf2, vf3;
    const u16* vp = vb + d * VST;
    vf0.q = *(const uint4*)(vp + (g << 3));
    vf1.q = *(const uint4*)(vp + 32 + (g << 3));
    vp += 16 * VST;
    vf2.q = *(const uint4*)(vp + (g << 3));
    vf3.q = *(const uint4*)(vp + 32 + (g << 3));
    accA0 = __builtin_amdgcn_mfma_f32_16x16x32_bf16(vf0.v, pbA0.v, accA0, 0, 0, 0);
    accA0 = __builtin_amdgcn_mfma_f32_16x16x32_bf16(vf1.v, pbA1.v, accA0, 0, 0, 0);
    accA1 = __builtin_amdgcn_mfma_f32_16x16x32_bf16(vf2.v, pbA0.v, accA1, 0, 0, 0);
    accA1 = __builtin_amdgcn_mfma_f32_16x16x32_bf16(vf3.v, pbA1.v, accA1, 0, 0, 0);
    accB0 = __builtin_amdgcn_mfma_f32_16x16x32_bf16(vf0.v, pbB0.v, accB0, 0, 0, 0);
    accB0 = __builtin_amdgcn_mfma_f32_16x16x32_bf16(vf1.v, pbB1.v, accB0, 0, 0, 0);
    accB1 = __builtin_amdgcn_mfma_f32_16x16x32_bf16(vf2.v, pbB0.v, accB1, 0, 0, 0);
    accB1 = __builtin_amdgcn_mfma_f32_16x16x32_bf16(vf3.v, pbB1.v, accB1, 0, 0, 0);
  };

#pragma unroll 1
  for (int it = 0; it < nIter; ++it) {
    uint4 a, b, c, e;
    if (it < nIter - 1) {            // prefetch next 128 keys into registers
      gK += 4096; gV += 128;
      a = *(const uint4*)gK; b = *(const uint4*)(gK + 8);
      c = *(const uint4*)gV; e = *(const uint4*)(gV + 8);
    }
    compute(sK, sVT);
    compute(sK + 64 * KST, sVT + VSZ);
    __syncthreads();               // all reads of current stage done
    if (it < nIter - 1) {
      *(uint4*)wK = a; *(uint4*)(wK + 8) = b;   // vmcnt drained under compute
      *(uint4*)wV = c; *(uint4*)(wV + 8) = e;
      __syncthreads();             // stage visible
    }
  }

  // denominators: accL*.x of lanes g==0 hold col sums (col = d = qrow-in-16)
  if (g == 0) {
    lsumP[((z * NH + h) << 12) + qrowA] = accLA.x;
    lsumP[((z * NH + h) << 12) + qrowB] = accLB.x;
  }
  // unnormalized partial O
  float* cpA = accP + z * (NN * 256) + (qrowA << 8) + (h << 5) + (g << 2);
  *(float4*)cpA        = make_float4(accA0.x, accA0.y, accA0.z, accA0.w);
  *(float4*)(cpA + 16) = make_float4(accA1.x, accA1.y, accA1.z, accA1.w);
  float* cpB = accP + z * (NN * 256) + (qrowB << 8) + (h << 5) + (g << 2);
  *(float4*)cpB        = make_float4(accB0.x, accB0.y, accB0.z, accB0.w);
  *(float4*)(cpB + 16) = make_float4(accB1.x, accB1.y, accB1.z, accB1.w);
}

// ---------------- fused combine + output projection (1024 blocks, 4 rows each) ----
// out[n][c] = bo[c] + sum_j ((sum_s accP[s][n][j]) / (sum_s lsum[s][h(j)][n])) * Wo[j][c]
__global__ __launch_bounds__(256) void out_fused_kernel(
    const float* __restrict__ accP, const float* __restrict__ lsumP,
    const float* __restrict__ Wo, const float* __restrict__ bo,
    float* __restrict__ out, int S)
{
  __shared__ float cn[4][256];     // normalized concat rows (4 KB)
  __shared__ float sQ[4][4][16];   // per (row, kslice, col) partials
  const int tid = threadIdx.x;
  const int n0 = blockIdx.x << 2;

  // stage cn: thread (r = tid>>6, u = tid&63) handles j = 4u..4u+3 of row n0+r
  {
    const int r = tid >> 6, u = tid & 63;
    const int n = n0 + r;
    float4 o = make_float4(0.f, 0.f, 0.f, 0.f);
    for (int s = 0; s < S; ++s) {
      const float4 v = *(const float4*)(accP + (size_t)s * (NN * 256) + (n << 8) + (u << 2));
      o.x += v.x; o.y += v.y; o.z += v.z; o.w += v.w;
    }
    const int hh = u >> 3;         // head of j-range (4 | 32, no straddle)
    float l = 0.f;
    for (int s = 0; s < S; ++s) l += lsumP[((s * NH + hh) << 12) + n];
    const float inv = 1.0f / l;
    *(float4*)&cn[r][u << 2] = make_float4(o.x * inv, o.y * inv, o.z * inv, o.w * inv);
  }
  __syncthreads();

  // GEMM: thread (r = tid>>6, ks = (tid>>4)&3, c = tid&15), 64 j per thread
  {
    const int r = tid >> 6, ks = (tid >> 4) & 3, c = tid & 15;
    const float* cr = &cn[r][ks << 6];
    const float* wp = Wo + (ks << 6) * 16 + c;
    float a = 0.f;
#pragma unroll
    for (int jj = 0; jj < 64; ++jj) {
      const int j2 = (jj + (ks << 4)) & 63;   // ks-rotation: 2-way LDS banks max
      a = fmaf(cr[j2], wp[j2 * 16], a);
    }
    sQ[r][ks][c] = a;
  }
  __syncthreads();

  if (tid < 64) {
    const int r = tid >> 4, c = tid & 15;
    float v = bo[c] + ((sQ[r][0][c] + sQ[r][1][c]) + (sQ[r][2][c] + sQ[r][3][c]));
    out[((n0 + r) << 4) + c] = v;
  }
}

extern "C" void kernel_launch(void* const* d_in, const int* in_sizes, int n_in,
                              void* d_out, int out_size, void* d_ws, size_t ws_size,
                              hipStream_t stream) {
  const float* x  = (const float*)d_in[0];
  const float* y  = (const float*)d_in[1];
  const float* Wq = (const float*)d_in[2];
  const float* bq = (const float*)d_in[3];
  const float* Wk = (const float*)d_in[4];
  const float* bk = (const float*)d_in[5];
  const float* Wv = (const float*)d_in[6];
  const float* bv = (const float*)d_in[7];
  const float* Wo = (const float*)d_in[8];
  const float* bo = (const float*)d_in[9];
  float* out = (float*)d_out;

  u16* qs = (u16*)d_ws;                       // [8][4096][32] bf16  (2 MB)
  u16* ks = qs + (NH * NN * 32);              // [8][4096][32] bf16  (2 MB)
  u16* vT = ks + (NH * MM * 32);              // [8][32][4096] bf16  (2 MB, key-permuted)
  float* accP = (float*)(vT + (NH * MM * 32)); // [S][4096][256] f32 partials
  // key-split by available scratch: S=4 needs 6 + 16 + 0.5 MB
  const int S = (ws_size >= (size_t)(6 + 16) * 1024 * 1024 + 512 * 1024) ? 4 : 1;
  float* lsumP = accP + (size_t)S * (NN * 256); // [S][8][4096] f32

  hipLaunchKernelGGL(proj_kernel, dim3(384), dim3(256), 0, stream,
                     x, y, Wq, bq, Wk, bk, Wv, bv, qs, ks, vT);
  hipLaunchKernelGGL(flash_kernel, dim3(32, NH, S), dim3(256), 0, stream,
                     qs, ks, vT, accP, lsumP);
  hipLaunchKernelGGL(out_fused_kernel, dim3(1024), dim3(256), 0, stream,
                     accP, lsumP, Wo, bo, out, S);
}